// Round 1
// baseline (698.821 us; speedup 1.0000x reference)
//
#include <hip/hip_runtime.h>

typedef unsigned int u32;
typedef unsigned short u16;

#define EPSV 1e-5f
#define NEGV -9.0e15f

__device__ __forceinline__ u16 f2bf(float f) {
  u32 u = __float_as_uint(f);
  u32 r = u + 0x7FFFu + ((u >> 16) & 1u);
  return (u16)(r >> 16);
}
__device__ __forceinline__ float bf2f(u16 h) {
  return __uint_as_float(((u32)h) << 16);
}

// ---------------- prep 1: fold BN params, effective bias ----------------
__global__ void k_prep1(const float* __restrict__ bn1g, const float* __restrict__ bn1b,
                        const float* __restrict__ bn1m, const float* __restrict__ bn1v,
                        const float* __restrict__ bn2g, const float* __restrict__ bn2b,
                        const float* __restrict__ bn2m, const float* __restrict__ bn2v,
                        const float* __restrict__ b3, const float* __restrict__ b5,
                        const float* __restrict__ b7, const float* __restrict__ wf,
                        const float* __restrict__ bfv,
                        float* __restrict__ s1, float* __restrict__ t1,
                        float* __restrict__ s2, float* __restrict__ beff) {
  int tid = threadIdx.x;
  if (tid < 192) {
    float sc = bn1g[tid] / sqrtf(bn1v[tid] + EPSV);
    s1[tid] = sc;
    t1[tid] = bn1b[tid] - bn1m[tid] * sc;
    float sc2 = bn2g[tid] / sqrtf(bn2v[tid] + EPSV);
    s2[tid] = sc2;
  }
  if (tid < 64) {
    float acc = bfv[tid];
    for (int io = 0; io < 192; ++io) {
      int i = io / 64, o = io % 64;
      float sc2 = bn2g[io] / sqrtf(bn2v[io] + EPSV);
      float t2 = bn2b[io] - bn2m[io] * sc2;
      float bi = (i == 0) ? b3[o] : ((i == 1) ? b5[o] : b7[o]);
      acc += wf[tid * 192 + io] * (sc2 * bi + t2);
    }
    beff[tid] = acc;
  }
}

// ---------------- prep 2: effective conv weights ----------------
// Weff[(k)][c][o2], k = 0..14 (branch0: 0..2, branch1: 3..7, branch2: 8..14)
__global__ void k_weff(const float* __restrict__ wf, const float* __restrict__ s2,
                       const float* __restrict__ w3, const float* __restrict__ w5,
                       const float* __restrict__ w7, float* __restrict__ Weff) {
  int flat = blockIdx.x * 256 + threadIdx.x;  // < 61440
  int o2 = flat & 63;
  int c = (flat >> 6) & 63;
  int k = flat >> 12;
  const float* w;
  int ks, dt, ib;
  if (k < 3)      { w = w3; ks = 3; dt = k;     ib = 0; }
  else if (k < 8) { w = w5; ks = 5; dt = k - 3; ib = 1; }
  else            { w = w7; ks = 7; dt = k - 8; ib = 2; }
  float acc = 0.f;
  for (int o = 0; o < 64; ++o)
    acc += wf[o2 * 192 + ib * 64 + o] * s2[ib * 64 + o] * w[(o * 64 + c) * ks + dt];
  Weff[flat] = acc;
}

// ---------------- GAT: one block per (b,t) graph ----------------
// writes xg bf16 in layout [b][v][t][c]
__global__ __launch_bounds__(256) void k_gat(const float* __restrict__ x,
                                             const float* __restrict__ adj,
                                             const float* __restrict__ Wg,
                                             const float* __restrict__ ag,
                                             u16* __restrict__ xg) {
  __shared__ float sh[25 * 65];
  __shared__ float sWh[25 * 68];
  __shared__ float satt[625];
  __shared__ float se1[32], se2[32];
  __shared__ float sadj[625];
  int tid = threadIdx.x;
  int n = blockIdx.x;
  int b = n >> 8, t = n & 255;
  const float* xbase = x + ((size_t)b * 64 * 256 + t) * 25;  // + c*6400 + v
  for (int idx = tid; idx < 1600; idx += 256) {
    int c = idx / 25, v = idx - c * 25;
    sh[v * 65 + c] = xbase[c * 6400 + v];
  }
  for (int idx = tid; idx < 625; idx += 256) sadj[idx] = adj[idx];
  __syncthreads();
  // Wh[v][d] = sum_c h[v][c] * W[c][d]; 4-wide d register tile, W rows from L1
  for (int q = tid; q < 400; q += 256) {
    int v = q >> 4, d0 = (q & 15) << 2;
    float ax = 0.f, ay = 0.f, az = 0.f, aw = 0.f;
#pragma unroll 8
    for (int c = 0; c < 64; ++c) {
      float hv = sh[v * 65 + c];
      const float4 wr = *reinterpret_cast<const float4*>(Wg + c * 64 + d0);
      ax = fmaf(hv, wr.x, ax); ay = fmaf(hv, wr.y, ay);
      az = fmaf(hv, wr.z, az); aw = fmaf(hv, wr.w, aw);
    }
    float4 r; r.x = ax; r.y = ay; r.z = az; r.w = aw;
    *reinterpret_cast<float4*>(&sWh[v * 68 + d0]) = r;
  }
  __syncthreads();
  // e1/e2 (two parallel waves)
  if (tid < 25) {
    float acc = 0.f;
    for (int d = 0; d < 64; ++d) acc += sWh[tid * 68 + d] * ag[d];
    se1[tid] = acc;
  } else if (tid >= 64 && tid < 89) {
    int u = tid - 64;
    float acc = 0.f;
    for (int d = 0; d < 64; ++d) acc += sWh[u * 68 + d] * ag[64 + d];
    se2[u] = acc;
  }
  __syncthreads();
  // masked softmax rows
  if (tid < 25) {
    int u = tid;
    float ev[25];
    float m = -1e30f;
#pragma unroll
    for (int v = 0; v < 25; ++v) {
      float e = se1[u] + se2[v];
      e = (e > 0.f) ? e : 0.2f * e;           // leaky_relu(0.2)
      e = (sadj[u * 25 + v] > 0.f) ? e : NEGV;
      ev[v] = e;
      m = fmaxf(m, e);
    }
    float s = 0.f;
#pragma unroll
    for (int v = 0; v < 25; ++v) { ev[v] = expf(ev[v] - m); s += ev[v]; }
    float inv = 1.f / s;
#pragma unroll
    for (int v = 0; v < 25; ++v) satt[u * 25 + v] = ev[v] * inv;
  }
  __syncthreads();
  // g = elu(att @ Wh), bf16 store, layout [b][u][t][d]
  u16* xgb = xg + ((size_t)(b * 25) * 256 + t) * 64;
  for (int q = tid; q < 400; q += 256) {
    int u = q >> 4, d0 = (q & 15) << 2;
    float ax = 0.f, ay = 0.f, az = 0.f, aw = 0.f;
#pragma unroll
    for (int v = 0; v < 25; ++v) {
      float av = satt[u * 25 + v];
      const float4 wh = *reinterpret_cast<const float4*>(&sWh[v * 68 + d0]);
      ax = fmaf(av, wh.x, ax); ay = fmaf(av, wh.y, ay);
      az = fmaf(av, wh.z, az); aw = fmaf(av, wh.w, aw);
    }
    ax = (ax > 0.f) ? ax : expf(ax) - 1.f;
    ay = (ay > 0.f) ? ay : expf(ay) - 1.f;
    az = (az > 0.f) ? az : expf(az) - 1.f;
    aw = (aw > 0.f) ? aw : expf(aw) - 1.f;
    ushort4 pk;
    pk.x = f2bf(ax); pk.y = f2bf(ay); pk.z = f2bf(az); pk.w = f2bf(aw);
    *reinterpret_cast<ushort4*>(xgb + (size_t)u * 16384 + d0) = pk;
  }
}

// ---------------- fused 3-branch conv (+bn1+relu in, bn2+wf folded) ----------------
// block = (b, v, t-tile 64); writes cw bf16 [b][v][t][o]
#define CONV_BRANCH(KS, WOFF, ABASE)                                                   \
  {                                                                                    \
    const float* abase_ = (ABASE);                                                     \
    _Pragma("unroll 2") for (int c = 0; c < 64; ++c) {                                 \
      const float* ar = abase_ + c * 72;                                               \
      float4 A0 = *reinterpret_cast<const float4*>(ar);                                \
      float4 A1 = *reinterpret_cast<const float4*>(ar + 4);                            \
      float4 A2 = (KS > 3) ? *reinterpret_cast<const float4*>(ar + 8) : A0;            \
      float a[12] = {A0.x, A0.y, A0.z, A0.w, A1.x, A1.y, A1.z, A1.w,                   \
                     A2.x, A2.y, A2.z, A2.w};                                          \
      _Pragma("unroll") for (int dt = 0; dt < KS; ++dt) {                              \
        const float4 w = *reinterpret_cast<const float4*>(                             \
            Weff + (WOFF) + ((dt * 64 + c) << 6) + (og << 2));                         \
        _Pragma("unroll") for (int ti = 0; ti < 4; ++ti) {                             \
          float av = a[dt + ti + ((7 - (KS)) / 2)];                                    \
          acc[0][ti] = fmaf(w.x, av, acc[0][ti]);                                      \
          acc[1][ti] = fmaf(w.y, av, acc[1][ti]);                                      \
          acc[2][ti] = fmaf(w.z, av, acc[2][ti]);                                      \
          acc[3][ti] = fmaf(w.w, av, acc[3][ti]);                                      \
        }                                                                              \
      }                                                                                \
    }                                                                                  \
  }

__global__ __launch_bounds__(256) void k_conv(const u16* __restrict__ xg,
                                              const float* __restrict__ Weff,
                                              const float* __restrict__ beff,
                                              const float* __restrict__ s1g,
                                              const float* __restrict__ t1g,
                                              u16* __restrict__ cw) {
  __shared__ float sact[3 * 64 * 72];
  __shared__ float ls1[192], lt1[192];
  int tid = threadIdx.x;
  int bid = blockIdx.x;
  int v = bid % 25;
  int r = bid / 25;
  int tb = r & 3;
  int b = r >> 2;
  int t0 = tb << 6;
  if (tid < 192) { ls1[tid] = s1g[tid]; lt1[tid] = t1g[tid]; }
  __syncthreads();
  const u16* xbase = xg + (size_t)(b * 25 + v) * 256 * 64;
  for (int idx = tid; idx < 13440; idx += 256) {
    int i = idx / 4480;
    int rr = idx - i * 4480;
    int s = rr >> 6;
    int c = rr & 63;
    int t_in = t0 - 3 + s;
    float a = 0.f;
    if (t_in >= 0 && t_in < 256) {
      float val = bf2f(xbase[t_in * 64 + c]);
      a = fmaxf(val * ls1[i * 64 + c] + lt1[i * 64 + c], 0.f);
    }
    sact[(i * 64 + c) * 72 + s] = a;
  }
  __syncthreads();
  int og = tid & 15, tg = tid >> 4;
  float acc[4][4];
#pragma unroll
  for (int oi = 0; oi < 4; ++oi)
#pragma unroll
    for (int ti = 0; ti < 4; ++ti) acc[oi][ti] = 0.f;

  CONV_BRANCH(3, 0, sact + tg * 4)
  CONV_BRANCH(5, 3 * 4096, sact + 4608 + tg * 4)
  CONV_BRANCH(7, 8 * 4096, sact + 9216 + tg * 4)

  const float4 bv = *reinterpret_cast<const float4*>(beff + og * 4);
  u16* obase = cw + ((size_t)(b * 25 + v) * 256 + t0) * 64;
#pragma unroll
  for (int ti = 0; ti < 4; ++ti) {
    int t = tg * 4 + ti;
    ushort4 pk;
    pk.x = f2bf(acc[0][ti] + bv.x);
    pk.y = f2bf(acc[1][ti] + bv.y);
    pk.z = f2bf(acc[2][ti] + bv.z);
    pk.w = f2bf(acc[3][ti] + bv.w);
    *reinterpret_cast<ushort4*>(obase + (size_t)t * 64 + (og << 2)) = pk;
  }
}

// ---------------- transpose [b][v][t][o] bf16 -> [b][o][t][v] fp32 ----------------
__global__ __launch_bounds__(256) void k_tr(const u16* __restrict__ cw,
                                            float* __restrict__ out) {
  __shared__ u16 sld[25 * 1042];
  int tid = threadIdx.x;
  int bid = blockIdx.x;
  int b = bid >> 4, tb = bid & 15;
  int t0 = tb << 4;
  const u32* src = reinterpret_cast<const u32*>(cw);
  for (int idx = tid; idx < 12800; idx += 256) {
    int v = idx / 512;
    int r2 = idx - v * 512;
    u32 val = src[((size_t)(b * 25 + v) * 256 + t0) * 32 + r2];
    *reinterpret_cast<u32*>(&sld[v * 1042 + r2 * 2]) = val;
  }
  __syncthreads();
  float* obase = out + (size_t)b * 64 * 6400 + t0 * 25;
  for (int o = 0; o < 64; ++o) {
    for (int j = tid; j < 400; j += 256) {
      int t = j / 25;
      int v = j - t * 25;
      obase[(size_t)o * 6400 + j] = bf2f(sld[v * 1042 + t * 64 + o]);
    }
  }
}

extern "C" void kernel_launch(void* const* d_in, const int* in_sizes, int n_in,
                              void* d_out, int out_size, void* d_ws, size_t ws_size,
                              hipStream_t stream) {
  (void)in_sizes; (void)n_in; (void)out_size; (void)ws_size;
  const float* x    = (const float*)d_in[0];
  const float* adj  = (const float*)d_in[1];
  const float* Wg   = (const float*)d_in[2];
  const float* ag   = (const float*)d_in[3];
  const float* bn1g = (const float*)d_in[4];
  const float* bn1b = (const float*)d_in[5];
  const float* bn1m = (const float*)d_in[6];
  const float* bn1v = (const float*)d_in[7];
  const float* w3   = (const float*)d_in[8];
  const float* b3   = (const float*)d_in[9];
  const float* w5   = (const float*)d_in[10];
  const float* b5   = (const float*)d_in[11];
  const float* w7   = (const float*)d_in[12];
  const float* b7   = (const float*)d_in[13];
  const float* bn2g = (const float*)d_in[14];
  const float* bn2b = (const float*)d_in[15];
  const float* bn2m = (const float*)d_in[16];
  const float* bn2v = (const float*)d_in[17];
  const float* wf   = (const float*)d_in[18];
  const float* bfv  = (const float*)d_in[19];

  char* ws  = (char*)d_ws;
  u16* xg   = (u16*)ws;                       // 13,107,200 bf16 = 26,214,400 B
  u16* cw   = (u16*)(ws + 26214400);          // 13,107,200 bf16 = 26,214,400 B
  float* Weff = (float*)(ws + 52428800);      // 61,440 f32
  float* beff = Weff + 61440;                 // 64
  float* s1   = beff + 64;                    // 192
  float* t1   = s1 + 192;                     // 192
  float* s2   = t1 + 192;                     // 192   (total ~52.7 MB)
  float* out  = (float*)d_out;

  k_prep1<<<1, 256, 0, stream>>>(bn1g, bn1b, bn1m, bn1v, bn2g, bn2b, bn2m, bn2v,
                                 b3, b5, b7, wf, bfv, s1, t1, s2, beff);
  k_weff<<<240, 256, 0, stream>>>(wf, s2, w3, w5, w7, Weff);
  k_gat<<<8192, 256, 0, stream>>>(x, adj, Wg, ag, xg);
  k_conv<<<3200, 256, 0, stream>>>(xg, Weff, beff, s1, t1, cw);
  k_tr<<<512, 256, 0, stream>>>(cw, out);
}

// Round 7
// 465.669 us; speedup vs baseline: 1.5007x; 1.5007x over previous
//
#include <hip/hip_runtime.h>

typedef unsigned int u32;
typedef unsigned short u16;
typedef short bf16x8 __attribute__((ext_vector_type(8)));
typedef float f32x4 __attribute__((ext_vector_type(4)));

#define EPSV 1e-5f
#define NEGV -9.0e15f

__device__ __forceinline__ u16 f2bf(float f) {
  u32 u = __float_as_uint(f);
  u32 r = u + 0x7FFFu + ((u >> 16) & 1u);
  return (u16)(r >> 16);
}
__device__ __forceinline__ float bf2f(u16 h) {
  return __uint_as_float(((u32)h) << 16);
}

// ---------------- prep 1: fold BN params, effective bias ----------------
__global__ void k_prep1(const float* __restrict__ bn1g, const float* __restrict__ bn1b,
                        const float* __restrict__ bn1m, const float* __restrict__ bn1v,
                        const float* __restrict__ bn2g, const float* __restrict__ bn2b,
                        const float* __restrict__ bn2m, const float* __restrict__ bn2v,
                        const float* __restrict__ b3, const float* __restrict__ b5,
                        const float* __restrict__ b7, const float* __restrict__ wf,
                        const float* __restrict__ bfv,
                        float* __restrict__ s1, float* __restrict__ t1,
                        float* __restrict__ s2, float* __restrict__ beff) {
  int tid = threadIdx.x;
  if (tid < 192) {
    float sc = bn1g[tid] / sqrtf(bn1v[tid] + EPSV);
    s1[tid] = sc;
    t1[tid] = bn1b[tid] - bn1m[tid] * sc;
    float sc2 = bn2g[tid] / sqrtf(bn2v[tid] + EPSV);
    s2[tid] = sc2;
  }
  if (tid < 64) {
    float acc = bfv[tid];
    for (int io = 0; io < 192; ++io) {
      int i = io / 64, o = io % 64;
      float sc2 = bn2g[io] / sqrtf(bn2v[io] + EPSV);
      float t2 = bn2b[io] - bn2m[io] * sc2;
      float bi = (i == 0) ? b3[o] : ((i == 1) ? b5[o] : b7[o]);
      acc += wf[tid * 192 + io] * (sc2 * bi + t2);
    }
    beff[tid] = acc;
  }
}

// ---------------- weight pack: Weff (bn2+wf folded) in MFMA B-fragment layout ----------------
// Bpack[kk][nf][lane][j] = bf16( Weff[k][o] ), k = kk*32 + (lane>>4)*8 + j,
// o = nf*16 + (lane&15); GEMM k = s*64 + c, s=slot(branch,dt), c=in-channel.
__global__ void k_wpack(const float* __restrict__ wf, const float* __restrict__ s2,
                        const float* __restrict__ w3, const float* __restrict__ w5,
                        const float* __restrict__ w7, u16* __restrict__ Bpack) {
  int idx = blockIdx.x * 256 + threadIdx.x;  // < 7680
  int kk = idx >> 8;
  int rem = idx & 255;
  int nf = rem >> 6;
  int lane = rem & 63;
  int o2 = nf * 16 + (lane & 15);
  int k0 = kk * 32 + (lane >> 4) * 8;
  short out[8];
#pragma unroll
  for (int j = 0; j < 8; ++j) {
    int k = k0 + j;
    int s = k >> 6, c = k & 63;
    const float* w;
    int ks, dt, ib;
    if (s < 3)      { w = w3; ks = 3; dt = s;     ib = 0; }
    else if (s < 8) { w = w5; ks = 5; dt = s - 3; ib = 1; }
    else            { w = w7; ks = 7; dt = s - 8; ib = 2; }
    float acc = 0.f;
    for (int o = 0; o < 64; ++o)
      acc += wf[o2 * 192 + ib * 64 + o] * s2[ib * 64 + o] * w[(o * 64 + c) * ks + dt];
    out[j] = (short)f2bf(acc);
  }
  bf16x8 pk;
#pragma unroll
  for (int j = 0; j < 8; ++j) pk[j] = out[j];
  *reinterpret_cast<bf16x8*>(Bpack + (size_t)idx * 8) = pk;
}

// ---------------- GAT: one block per (b,t) graph ----------------
// writes xg bf16 in layout [b][v][t][c]
__global__ __launch_bounds__(256) void k_gat(const float* __restrict__ x,
                                             const float* __restrict__ adj,
                                             const float* __restrict__ Wg,
                                             const float* __restrict__ ag,
                                             u16* __restrict__ xg) {
  __shared__ float sh[25 * 65];
  __shared__ float sWh[25 * 68];
  __shared__ float satt[625];
  __shared__ float se1[32], se2[32];
  __shared__ float sadj[625];
  int tid = threadIdx.x;
  int n = blockIdx.x;
  int b = n >> 8, t = n & 255;
  const float* xbase = x + ((size_t)b * 64 * 256 + t) * 25;  // + c*6400 + v
  for (int idx = tid; idx < 1600; idx += 256) {
    int c = idx / 25, v = idx - c * 25;
    sh[v * 65 + c] = xbase[c * 6400 + v];
  }
  for (int idx = tid; idx < 625; idx += 256) sadj[idx] = adj[idx];
  __syncthreads();
  // Wh[v][d] = sum_c h[v][c] * W[c][d]
  for (int q = tid; q < 400; q += 256) {
    int v = q >> 4, d0 = (q & 15) << 2;
    float ax = 0.f, ay = 0.f, az = 0.f, aw = 0.f;
#pragma unroll 8
    for (int c = 0; c < 64; ++c) {
      float hv = sh[v * 65 + c];
      const float4 wr = *reinterpret_cast<const float4*>(Wg + c * 64 + d0);
      ax = fmaf(hv, wr.x, ax); ay = fmaf(hv, wr.y, ay);
      az = fmaf(hv, wr.z, az); aw = fmaf(hv, wr.w, aw);
    }
    float4 r; r.x = ax; r.y = ay; r.z = az; r.w = aw;
    *reinterpret_cast<float4*>(&sWh[v * 68 + d0]) = r;
  }
  __syncthreads();
  // e1/e2: 4 lanes per (u,vec) item, shuffle-reduce
  if ((tid >> 2) < 50) {
    int q = tid >> 2, sub = tid & 3;
    int u = q >> 1, vec = q & 1;
    const float* av = ag + vec * 64;
    float acc = 0.f;
    int d0 = sub * 16;
#pragma unroll
    for (int d = 0; d < 16; ++d) acc = fmaf(sWh[u * 68 + d0 + d], av[d0 + d], acc);
    acc += __shfl_xor(acc, 1);
    acc += __shfl_xor(acc, 2);
    if (sub == 0) {
      if (vec) se2[u] = acc; else se1[u] = acc;
    }
  }
  __syncthreads();
  // masked softmax rows: 8 lanes per row u
  if ((tid >> 3) < 25) {
    int u = tid >> 3, sub = tid & 7;
    float ev[4];
    int cnt = 0;
    float m = -1e30f;
    for (int v = sub; v < 25; v += 8) {
      float e = se1[u] + se2[v];
      e = (e > 0.f) ? e : 0.2f * e;           // leaky_relu(0.2)
      e = (sadj[u * 25 + v] > 0.f) ? e : NEGV;
      ev[cnt++] = e;
      m = fmaxf(m, e);
    }
    m = fmaxf(m, __shfl_xor(m, 1));
    m = fmaxf(m, __shfl_xor(m, 2));
    m = fmaxf(m, __shfl_xor(m, 4));
    float s = 0.f;
    for (int k = 0; k < cnt; ++k) { ev[k] = __expf(ev[k] - m); s += ev[k]; }
    s += __shfl_xor(s, 1);
    s += __shfl_xor(s, 2);
    s += __shfl_xor(s, 4);
    float inv = 1.f / s;
    cnt = 0;
    for (int v = sub; v < 25; v += 8) satt[u * 25 + v] = ev[cnt++] * inv;
  }
  __syncthreads();
  // g = elu(att @ Wh), bf16 store, layout [b][u][t][d]
  u16* xgb = xg + ((size_t)(b * 25) * 256 + t) * 64;
  for (int q = tid; q < 400; q += 256) {
    int u = q >> 4, d0 = (q & 15) << 2;
    float ax = 0.f, ay = 0.f, az = 0.f, aw = 0.f;
#pragma unroll
    for (int v = 0; v < 25; ++v) {
      float av = satt[u * 25 + v];
      const float4 wh = *reinterpret_cast<const float4*>(&sWh[v * 68 + d0]);
      ax = fmaf(av, wh.x, ax); ay = fmaf(av, wh.y, ay);
      az = fmaf(av, wh.z, az); aw = fmaf(av, wh.w, aw);
    }
    ax = (ax > 0.f) ? ax : __expf(ax) - 1.f;
    ay = (ay > 0.f) ? ay : __expf(ay) - 1.f;
    az = (az > 0.f) ? az : __expf(az) - 1.f;
    aw = (aw > 0.f) ? aw : __expf(aw) - 1.f;
    ushort4 pk;
    pk.x = f2bf(ax); pk.y = f2bf(ay); pk.z = f2bf(az); pk.w = f2bf(aw);
    *reinterpret_cast<ushort4*>(xgb + (size_t)u * 16384 + d0) = pk;
  }
}

// ---------------- fused 3-branch conv via MFMA ----------------
// block = (b, v, t-tile 128); A-tile (3-branch activations) in swizzled LDS,
// B (folded weights) streamed from L2 in fragment layout. Writes cw bf16 [b][v][t][o].
// Swizzle: physical chunk = logical chunk ^ (row&7); XOR touches only low 3 bits,
// so each branch's 8-chunk band is closed under it (write side MUST use the same
// full-chunk XOR as the read side — (8+co)^(8+r7) collapses bands! that was the NaN).
__global__ __launch_bounds__(256) void k_conv(const u16* __restrict__ xg,
                                              const u16* __restrict__ Bpack,
                                              const float* __restrict__ beff,
                                              const float* __restrict__ s1g,
                                              const float* __restrict__ t1g,
                                              u16* __restrict__ cw) {
  __shared__ __align__(16) u16 Asm[134 * 192];  // 51456 B; rows r=0..133, k=i*64+c, XOR-swizzled 16B chunks
  __shared__ float ls1[192], lt1[192];
  int tid = threadIdx.x;
  int bid = blockIdx.x;  // 1600 = 32*25*2
  int th = bid & 1;
  int v = (bid >> 1) % 25;
  int b = (bid >> 1) / 25;
  int t0 = th << 7;
  if (tid < 192) { ls1[tid] = s1g[tid]; lt1[tid] = t1g[tid]; }
  __syncthreads();

  // --- materialize branch activations: relu(xg*s1+t1), zero outside [0,256) ---
  const u16* xbase = xg + (size_t)(b * 25 + v) * 256 * 64;
  for (int it = tid; it < 1072; it += 256) {  // 134 rows x 8 c-octets
    int r = it >> 3, co = it & 7;
    int t_in = t0 - 3 + r;
    bf16x8 pk0, pk1, pk2;
    if (t_in >= 0 && t_in < 256) {
      bf16x8 raw = *reinterpret_cast<const bf16x8*>(xbase + (size_t)t_in * 64 + co * 8);
#pragma unroll
      for (int j = 0; j < 8; ++j) {
        float xv = bf2f((u16)raw[j]);
        int c = co * 8 + j;
        pk0[j] = (short)f2bf(fmaxf(fmaf(xv, ls1[c], lt1[c]), 0.f));
        pk1[j] = (short)f2bf(fmaxf(fmaf(xv, ls1[64 + c], lt1[64 + c]), 0.f));
        pk2[j] = (short)f2bf(fmaxf(fmaf(xv, ls1[128 + c], lt1[128 + c]), 0.f));
      }
    } else {
#pragma unroll
      for (int j = 0; j < 8; ++j) { pk0[j] = 0; pk1[j] = 0; pk2[j] = 0; }
    }
    int sw = co ^ (r & 7);  // low-3-bit XOR; band-preserving
    *reinterpret_cast<bf16x8*>(&Asm[r * 192 + ((sw)      << 3)]) = pk0;
    *reinterpret_cast<bf16x8*>(&Asm[r * 192 + ((8 + sw)  << 3)]) = pk1;
    *reinterpret_cast<bf16x8*>(&Asm[r * 192 + ((16 + sw) << 3)]) = pk2;
  }
  __syncthreads();

  // --- K-loop: 30 steps of 16x16x32 bf16 MFMA ---
  int w = tid >> 6, lane = tid & 63;
  int lrow = lane & 15, loct = lane >> 4;
  int mbase = w * 32 + lrow;  // + mf*16
  f32x4 acc[2][4];
#pragma unroll
  for (int m = 0; m < 2; ++m)
#pragma unroll
    for (int n = 0; n < 4; ++n)
#pragma unroll
      for (int rg = 0; rg < 4; ++rg) acc[m][n][rg] = 0.f;

  const int SHIFT[15] = {2, 3, 4, 1, 2, 3, 4, 5, 0, 1, 2, 3, 4, 5, 6};
  const int BR[15]    = {0, 0, 0, 1, 1, 1, 1, 1, 2, 2, 2, 2, 2, 2, 2};
  const bf16x8* Bp = reinterpret_cast<const bf16x8*>(Bpack);
#pragma unroll
  for (int s = 0; s < 15; ++s) {
    int i = BR[s];
#pragma unroll
    for (int h = 0; h < 2; ++h) {
      int kk = s * 2 + h;
      bf16x8 afr[2];
#pragma unroll
      for (int mf = 0; mf < 2; ++mf) {
        int r = mbase + mf * 16 + SHIFT[s];
        int chunk = i * 8 + (((h * 4 + loct)) ^ (r & 7));
        afr[mf] = *reinterpret_cast<const bf16x8*>(&Asm[r * 192 + (chunk << 3)]);
      }
#pragma unroll
      for (int nf = 0; nf < 4; ++nf) {
        bf16x8 bfr = Bp[(kk * 4 + nf) * 64 + lane];
        acc[0][nf] = __builtin_amdgcn_mfma_f32_16x16x32_bf16(afr[0], bfr, acc[0][nf], 0, 0, 0);
        acc[1][nf] = __builtin_amdgcn_mfma_f32_16x16x32_bf16(afr[1], bfr, acc[1][nf], 0, 0, 0);
      }
    }
  }
  __syncthreads();  // all A reads done; reuse Asm for C staging

  // --- epilogue: C/D layout col=lane&15 (=o), row=(lane>>4)*4+reg (=t) ---
  float be[4];
#pragma unroll
  for (int nf = 0; nf < 4; ++nf) be[nf] = beff[nf * 16 + lrow];
#pragma unroll
  for (int mf = 0; mf < 2; ++mf)
#pragma unroll
    for (int nf = 0; nf < 4; ++nf)
#pragma unroll
      for (int rg = 0; rg < 4; ++rg) {
        int trow = w * 32 + mf * 16 + loct * 4 + rg;
        Asm[trow * 64 + nf * 16 + lrow] = f2bf(acc[mf][nf][rg] + be[nf]);
      }
  __syncthreads();
  const float4* Cs = reinterpret_cast<const float4*>(Asm);
  float4* obase = reinterpret_cast<float4*>(cw + ((size_t)(b * 25 + v) * 256 + t0) * 64);
  for (int it2 = tid; it2 < 1024; it2 += 256) obase[it2] = Cs[it2];
}

// ---------------- transpose [b][v][t][o] bf16 -> [b][o][t][v] fp32 ----------------
__global__ __launch_bounds__(256) void k_tr(const u16* __restrict__ cw,
                                            float* __restrict__ out) {
  __shared__ u16 sld[25 * 1042];
  int tid = threadIdx.x;
  int bid = blockIdx.x;
  int b = bid >> 4, tb = bid & 15;
  int t0 = tb << 4;
  const u32* src = reinterpret_cast<const u32*>(cw);
  for (int idx = tid; idx < 12800; idx += 256) {
    int v = idx / 512;
    int r2 = idx - v * 512;
    u32 val = src[((size_t)(b * 25 + v) * 256 + t0) * 32 + r2];
    *reinterpret_cast<u32*>(&sld[v * 1042 + r2 * 2]) = val;
  }
  __syncthreads();
  float* obase = out + (size_t)b * 64 * 6400 + t0 * 25;
  for (int o = 0; o < 64; ++o) {
    for (int j = tid; j < 400; j += 256) {
      int t = j / 25;
      int v = j - t * 25;
      obase[(size_t)o * 6400 + j] = bf2f(sld[v * 1042 + t * 64 + o]);
    }
  }
}

extern "C" void kernel_launch(void* const* d_in, const int* in_sizes, int n_in,
                              void* d_out, int out_size, void* d_ws, size_t ws_size,
                              hipStream_t stream) {
  (void)in_sizes; (void)n_in; (void)out_size; (void)ws_size;
  const float* x    = (const float*)d_in[0];
  const float* adj  = (const float*)d_in[1];
  const float* Wg   = (const float*)d_in[2];
  const float* ag   = (const float*)d_in[3];
  const float* bn1g = (const float*)d_in[4];
  const float* bn1b = (const float*)d_in[5];
  const float* bn1m = (const float*)d_in[6];
  const float* bn1v = (const float*)d_in[7];
  const float* w3   = (const float*)d_in[8];
  const float* b3   = (const float*)d_in[9];
  const float* w5   = (const float*)d_in[10];
  const float* b5   = (const float*)d_in[11];
  const float* w7   = (const float*)d_in[12];
  const float* b7   = (const float*)d_in[13];
  const float* bn2g = (const float*)d_in[14];
  const float* bn2b = (const float*)d_in[15];
  const float* bn2m = (const float*)d_in[16];
  const float* bn2v = (const float*)d_in[17];
  const float* wf   = (const float*)d_in[18];
  const float* bfv  = (const float*)d_in[19];

  char* ws  = (char*)d_ws;
  u16* xg   = (u16*)ws;                       // 26,214,400 B
  u16* cw   = (u16*)(ws + 26214400);          // 26,214,400 B
  u16* Bpack = (u16*)(ws + 52428800);         // 122,880 B
  float* beff = (float*)(ws + 52551680);      // 64 f32
  float* s1   = beff + 64;                    // 192
  float* t1   = s1 + 192;                     // 192
  float* s2   = t1 + 192;                     // 192
  float* out  = (float*)d_out;

  k_prep1<<<1, 256, 0, stream>>>(bn1g, bn1b, bn1m, bn1v, bn2g, bn2b, bn2m, bn2v,
                                 b3, b5, b7, wf, bfv, s1, t1, s2, beff);
  k_wpack<<<30, 256, 0, stream>>>(wf, s2, w3, w5, w7, Bpack);
  k_gat<<<8192, 256, 0, stream>>>(x, adj, Wg, ag, xg);
  k_conv<<<1600, 256, 0, stream>>>(xg, Bpack, beff, s1, t1, cw);
  k_tr<<<512, 256, 0, stream>>>(cw, out);
}

// Round 8
// 393.668 us; speedup vs baseline: 1.7752x; 1.1829x over previous
//
#include <hip/hip_runtime.h>

typedef unsigned int u32;
typedef unsigned short u16;
typedef short bf16x8 __attribute__((ext_vector_type(8)));
typedef float f32x4 __attribute__((ext_vector_type(4)));

#define EPSV 1e-5f
#define NEGV -9.0e15f

__device__ __forceinline__ u16 f2bf(float f) {
  u32 u = __float_as_uint(f);
  u32 r = u + 0x7FFFu + ((u >> 16) & 1u);
  return (u16)(r >> 16);
}
__device__ __forceinline__ float bf2f(u16 h) {
  return __uint_as_float(((u32)h) << 16);
}

// ---------------- prep 1: fold BN params, effective bias ----------------
__global__ void k_prep1(const float* __restrict__ bn1g, const float* __restrict__ bn1b,
                        const float* __restrict__ bn1m, const float* __restrict__ bn1v,
                        const float* __restrict__ bn2g, const float* __restrict__ bn2b,
                        const float* __restrict__ bn2m, const float* __restrict__ bn2v,
                        const float* __restrict__ b3, const float* __restrict__ b5,
                        const float* __restrict__ b7, const float* __restrict__ wf,
                        const float* __restrict__ bfv,
                        float* __restrict__ s1, float* __restrict__ t1,
                        float* __restrict__ s2, float* __restrict__ beff) {
  int tid = threadIdx.x;
  if (tid < 192) {
    float sc = bn1g[tid] / sqrtf(bn1v[tid] + EPSV);
    s1[tid] = sc;
    t1[tid] = bn1b[tid] - bn1m[tid] * sc;
    float sc2 = bn2g[tid] / sqrtf(bn2v[tid] + EPSV);
    s2[tid] = sc2;
  }
  if (tid < 64) {
    float acc = bfv[tid];
    for (int io = 0; io < 192; ++io) {
      int i = io / 64, o = io % 64;
      float sc2 = bn2g[io] / sqrtf(bn2v[io] + EPSV);
      float t2 = bn2b[io] - bn2m[io] * sc2;
      float bi = (i == 0) ? b3[o] : ((i == 1) ? b5[o] : b7[o]);
      acc += wf[tid * 192 + io] * (sc2 * bi + t2);
    }
    beff[tid] = acc;
  }
}

// ---------------- weight pack: Weff (bn2+wf folded) in MFMA B-fragment layout ----------------
__global__ void k_wpack(const float* __restrict__ wf, const float* __restrict__ s2,
                        const float* __restrict__ w3, const float* __restrict__ w5,
                        const float* __restrict__ w7, u16* __restrict__ Bpack) {
  int idx = blockIdx.x * 256 + threadIdx.x;  // < 7680
  int kk = idx >> 8;
  int rem = idx & 255;
  int nf = rem >> 6;
  int lane = rem & 63;
  int o2 = nf * 16 + (lane & 15);
  int k0 = kk * 32 + (lane >> 4) * 8;
  short out[8];
#pragma unroll
  for (int j = 0; j < 8; ++j) {
    int k = k0 + j;
    int s = k >> 6, c = k & 63;
    const float* w;
    int ks, dt, ib;
    if (s < 3)      { w = w3; ks = 3; dt = s;     ib = 0; }
    else if (s < 8) { w = w5; ks = 5; dt = s - 3; ib = 1; }
    else            { w = w7; ks = 7; dt = s - 8; ib = 2; }
    float acc = 0.f;
    for (int o = 0; o < 64; ++o)
      acc += wf[o2 * 192 + ib * 64 + o] * s2[ib * 64 + o] * w[(o * 64 + c) * ks + dt];
    out[j] = (short)f2bf(acc);
  }
  bf16x8 pk;
#pragma unroll
  for (int j = 0; j < 8; ++j) pk[j] = out[j];
  *reinterpret_cast<bf16x8*>(Bpack + (size_t)idx * 8) = pk;
}

// ---------------- GAT B-pack: Wg augmented with e-columns, MFMA B-frag layout ----------------
// Bg[kk][nf][lane][j], k=kk*32+(lane>>4)*8+j (in-channel c), n=nf*16+(lane&15).
// n<64: Wg[k][n]; n=64/65: (W@a1) hi/lo; n=66/67: (W@a2) hi/lo; n>=68: 0.
__global__ void k_wg(const float* __restrict__ Wg, const float* __restrict__ ag,
                     u16* __restrict__ Bgp) {
  int i = blockIdx.x * 256 + threadIdx.x;
  if (i >= 640) return;
  int lane = i & 63;
  int nf = (i >> 6) % 5;
  int kk = i / 320;
  int k0 = kk * 32 + (lane >> 4) * 8;
  int n = nf * 16 + (lane & 15);
  bf16x8 pk;
#pragma unroll
  for (int j = 0; j < 8; ++j) {
    int k = k0 + j;
    float val;
    if (n < 64) {
      val = Wg[k * 64 + n];
    } else if (n < 68) {
      int which = n - 64;
      const float* a = ag + (which >> 1) * 64;
      float wa = 0.f;
      for (int d = 0; d < 64; ++d) wa += Wg[k * 64 + d] * a[d];
      float hi = bf2f(f2bf(wa));
      val = (which & 1) ? (wa - hi) : wa;
    } else {
      val = 0.f;
    }
    pk[j] = (short)f2bf(val);
  }
  *reinterpret_cast<bf16x8*>(Bgp + (size_t)i * 8) = pk;
}

// ---------------- GAT via MFMA: 8 graphs (t's) per block ----------------
// GEMM1: Wh(+e-cols) = h @ Waug  (M=208 pad, K=64, N=80).
// Softmax: 1 row/lane. PV: att @ Wh per graph (2x 16x16x32 MFMA).
// Writes xg bf16 [b][v][t][c].
__global__ __launch_bounds__(256) void k_gat2(const float* __restrict__ x,
                                              const float* __restrict__ adj,
                                              const u16* __restrict__ Bg,
                                              u16* __restrict__ xg) {
  __shared__ __align__(16) u16 A_s[13312];    // A-tile 208x64 octet-swizzled; reused as att[8][32][40]
  __shared__ __align__(16) u16 WhT_s[16384];  // [8][64 d][32 v], v-octet swz = (voct ^ ((n>>1)&3))
  __shared__ float e1_s[208], e2_s[208];
  __shared__ u16 adj_s[640];
  int tid = threadIdx.x;
  int bid = blockIdx.x;               // 1024 = 32 b x 32 t-tiles
  int b = bid >> 5, t0 = (bid & 31) << 3;

  // --- stage A: h[row=tl*25+v][c] = x[b][c][t0+tl][v], bf16, swizzled ---
  const float* xb = x + (size_t)b * 64 * 6400 + t0 * 25;
  for (int i = tid; i < 12800; i += 256) {
    int c = i / 200, row = i - c * 200;   // row = tl*25+v, contiguous in global
    float v = xb[c * 6400 + row];
    A_s[row * 64 + ((((c >> 3) ^ (row & 7))) << 3) + (c & 7)] = f2bf(v);
  }
  for (int i = tid; i < 625; i += 256) adj_s[i] = (adj[i] > 0.f) ? 1 : 0;
  // zero WhT pad rows v=25..31 (K-pad of PV must be clean)
  for (int i = tid; i < 3584; i += 256) {
    int v = 25 + (i % 7);
    int gn = i / 7;                      // g*64+n
    int n = gn & 63;
    WhT_s[gn * 32 + (((v >> 3) ^ ((n >> 1) & 3)) << 3) + (v & 7)] = 0;
  }
  __syncthreads();

  int wv = tid >> 6, lane = tid & 63;
  int l15 = lane & 15, l4 = lane >> 4;

  // --- GEMM1 ---
  const bf16x8* Bp = reinterpret_cast<const bf16x8*>(Bg);
  bf16x8 bg[2][5];
#pragma unroll
  for (int kk = 0; kk < 2; ++kk)
#pragma unroll
    for (int nf = 0; nf < 5; ++nf) bg[kk][nf] = Bp[(kk * 5 + nf) * 64 + lane];

  for (int mf = wv; mf < 13; mf += 4) {
    f32x4 acc[5];
#pragma unroll
    for (int nf = 0; nf < 5; ++nf)
#pragma unroll
      for (int rg = 0; rg < 4; ++rg) acc[nf][rg] = 0.f;
    int row = mf * 16 + l15;
    int r7 = row & 7;
    bf16x8 a0 = *reinterpret_cast<const bf16x8*>(&A_s[row * 64 + ((l4 ^ r7) << 3)]);
    bf16x8 a1 = *reinterpret_cast<const bf16x8*>(&A_s[row * 64 + (((4 + l4) ^ r7) << 3)]);
#pragma unroll
    for (int nf = 0; nf < 5; ++nf) {
      acc[nf] = __builtin_amdgcn_mfma_f32_16x16x32_bf16(a0, bg[0][nf], acc[nf], 0, 0, 0);
      acc[nf] = __builtin_amdgcn_mfma_f32_16x16x32_bf16(a1, bg[1][nf], acc[nf], 0, 0, 0);
    }
    // epilogue: D row = mf*16 + l4*4 + rg, col n = nf*16 + l15
#pragma unroll
    for (int rg = 0; rg < 4; ++rg) {
      int row_e = mf * 16 + (l4 << 2) + rg;
      float esum = acc[4][rg] + __shfl_xor(acc[4][rg], 1);
      if (row_e < 200) {
        int g = row_e / 25;
        int vv = row_e - g * 25;
#pragma unroll
        for (int nf = 0; nf < 4; ++nf) {
          int n = nf * 16 + l15;
          WhT_s[(g * 64 + n) * 32 + (((vv >> 3) ^ ((n >> 1) & 3)) << 3) + (vv & 7)] =
              f2bf(acc[nf][rg]);
        }
        if (l15 == 0) e1_s[row_e] = esum;
        else if (l15 == 2) e2_s[row_e] = esum;
      }
    }
  }
  __syncthreads();

  // --- masked softmax: graph g = tid>>5, row u = tid&31 ---
  {
    int g = tid >> 5, u = tid & 31;
    if (u < 25) {
      float e1 = e1_s[g * 25 + u];
      float ev[25];
      float m = -1e30f;
#pragma unroll
      for (int v = 0; v < 25; ++v) {
        float e = e1 + e2_s[g * 25 + v];
        e = (e > 0.f) ? e : 0.2f * e;
        e = adj_s[u * 25 + v] ? e : NEGV;
        ev[v] = e;
        m = fmaxf(m, e);
      }
      float s = 0.f;
#pragma unroll
      for (int v = 0; v < 25; ++v) { ev[v] = __expf(ev[v] - m); s += ev[v]; }
      float inv = 1.f / s;
      u16* arow = A_s + ((size_t)(g * 32 + u)) * 40;
#pragma unroll
      for (int v = 0; v < 25; ++v) arow[v] = f2bf(ev[v] * inv);
#pragma unroll
      for (int v = 25; v < 32; ++v) arow[v] = 0;
    }
  }
  __syncthreads();

  // --- PV: per (g, mf2): D = att @ Wh ---
  for (int un = wv; un < 16; un += 4) {
    int g = un >> 1, mf2 = un & 1;
    bf16x8 afr = *reinterpret_cast<const bf16x8*>(&A_s[(g * 32 + mf2 * 16 + l15) * 40 + (l4 << 3)]);
    f32x4 pacc[4];
#pragma unroll
    for (int nf = 0; nf < 4; ++nf)
#pragma unroll
      for (int rg = 0; rg < 4; ++rg) pacc[nf][rg] = 0.f;
#pragma unroll
    for (int nf = 0; nf < 4; ++nf) {
      int n = nf * 16 + l15;
      bf16x8 bfr = *reinterpret_cast<const bf16x8*>(
          &WhT_s[(g * 64 + n) * 32 + ((l4 ^ ((n >> 1) & 3)) << 3)]);
      pacc[nf] = __builtin_amdgcn_mfma_f32_16x16x32_bf16(afr, bfr, pacc[nf], 0, 0, 0);
    }
    int t = t0 + g;
#pragma unroll
    for (int nf = 0; nf < 4; ++nf)
#pragma unroll
      for (int rg = 0; rg < 4; ++rg) {
        int u = mf2 * 16 + (l4 << 2) + rg;
        if (u < 25) {
          float val = pacc[nf][rg];
          val = (val > 0.f) ? val : __expf(val) - 1.f;
          xg[(((size_t)(b * 25 + u)) * 256 + t) * 64 + nf * 16 + l15] = f2bf(val);
        }
      }
  }
}

// ---------------- fused 3-branch conv via MFMA (unchanged from R7) ----------------
__global__ __launch_bounds__(256) void k_conv(const u16* __restrict__ xg,
                                              const u16* __restrict__ Bpack,
                                              const float* __restrict__ beff,
                                              const float* __restrict__ s1g,
                                              const float* __restrict__ t1g,
                                              u16* __restrict__ cw) {
  __shared__ __align__(16) u16 Asm[134 * 192];
  __shared__ float ls1[192], lt1[192];
  int tid = threadIdx.x;
  int bid = blockIdx.x;  // 1600 = 32*25*2
  int th = bid & 1;
  int v = (bid >> 1) % 25;
  int b = (bid >> 1) / 25;
  int t0 = th << 7;
  if (tid < 192) { ls1[tid] = s1g[tid]; lt1[tid] = t1g[tid]; }
  __syncthreads();

  const u16* xbase = xg + (size_t)(b * 25 + v) * 256 * 64;
  for (int it = tid; it < 1072; it += 256) {
    int r = it >> 3, co = it & 7;
    int t_in = t0 - 3 + r;
    bf16x8 pk0, pk1, pk2;
    if (t_in >= 0 && t_in < 256) {
      bf16x8 raw = *reinterpret_cast<const bf16x8*>(xbase + (size_t)t_in * 64 + co * 8);
#pragma unroll
      for (int j = 0; j < 8; ++j) {
        float xv = bf2f((u16)raw[j]);
        int c = co * 8 + j;
        pk0[j] = (short)f2bf(fmaxf(fmaf(xv, ls1[c], lt1[c]), 0.f));
        pk1[j] = (short)f2bf(fmaxf(fmaf(xv, ls1[64 + c], lt1[64 + c]), 0.f));
        pk2[j] = (short)f2bf(fmaxf(fmaf(xv, ls1[128 + c], lt1[128 + c]), 0.f));
      }
    } else {
#pragma unroll
      for (int j = 0; j < 8; ++j) { pk0[j] = 0; pk1[j] = 0; pk2[j] = 0; }
    }
    int sw = co ^ (r & 7);
    *reinterpret_cast<bf16x8*>(&Asm[r * 192 + ((sw)      << 3)]) = pk0;
    *reinterpret_cast<bf16x8*>(&Asm[r * 192 + ((8 + sw)  << 3)]) = pk1;
    *reinterpret_cast<bf16x8*>(&Asm[r * 192 + ((16 + sw) << 3)]) = pk2;
  }
  __syncthreads();

  int w = tid >> 6, lane = tid & 63;
  int lrow = lane & 15, loct = lane >> 4;
  int mbase = w * 32 + lrow;
  f32x4 acc[2][4];
#pragma unroll
  for (int m = 0; m < 2; ++m)
#pragma unroll
    for (int n = 0; n < 4; ++n)
#pragma unroll
      for (int rg = 0; rg < 4; ++rg) acc[m][n][rg] = 0.f;

  const int SHIFT[15] = {2, 3, 4, 1, 2, 3, 4, 5, 0, 1, 2, 3, 4, 5, 6};
  const int BR[15]    = {0, 0, 0, 1, 1, 1, 1, 1, 2, 2, 2, 2, 2, 2, 2};
  const bf16x8* Bp = reinterpret_cast<const bf16x8*>(Bpack);
#pragma unroll
  for (int s = 0; s < 15; ++s) {
    int i = BR[s];
#pragma unroll
    for (int h = 0; h < 2; ++h) {
      int kk = s * 2 + h;
      bf16x8 afr[2];
#pragma unroll
      for (int mf = 0; mf < 2; ++mf) {
        int r = mbase + mf * 16 + SHIFT[s];
        int chunk = i * 8 + (((h * 4 + loct)) ^ (r & 7));
        afr[mf] = *reinterpret_cast<const bf16x8*>(&Asm[r * 192 + (chunk << 3)]);
      }
#pragma unroll
      for (int nf = 0; nf < 4; ++nf) {
        bf16x8 bfr = Bp[(kk * 4 + nf) * 64 + lane];
        acc[0][nf] = __builtin_amdgcn_mfma_f32_16x16x32_bf16(afr[0], bfr, acc[0][nf], 0, 0, 0);
        acc[1][nf] = __builtin_amdgcn_mfma_f32_16x16x32_bf16(afr[1], bfr, acc[1][nf], 0, 0, 0);
      }
    }
  }
  __syncthreads();

  float be[4];
#pragma unroll
  for (int nf = 0; nf < 4; ++nf) be[nf] = beff[nf * 16 + lrow];
#pragma unroll
  for (int mf = 0; mf < 2; ++mf)
#pragma unroll
    for (int nf = 0; nf < 4; ++nf)
#pragma unroll
      for (int rg = 0; rg < 4; ++rg) {
        int trow = w * 32 + mf * 16 + loct * 4 + rg;
        Asm[trow * 64 + nf * 16 + lrow] = f2bf(acc[mf][nf][rg] + be[nf]);
      }
  __syncthreads();
  const float4* Cs = reinterpret_cast<const float4*>(Asm);
  float4* obase = reinterpret_cast<float4*>(cw + ((size_t)(b * 25 + v) * 256 + t0) * 64);
  for (int it2 = tid; it2 < 1024; it2 += 256) obase[it2] = Cs[it2];
}

// ---------------- transpose [b][v][t][o] bf16 -> [b][o][t][v] fp32 ----------------
__global__ __launch_bounds__(256) void k_tr(const u16* __restrict__ cw,
                                            float* __restrict__ out) {
  __shared__ u16 sld[25 * 1042];
  int tid = threadIdx.x;
  int bid = blockIdx.x;
  int b = bid >> 4, tb = bid & 15;
  int t0 = tb << 4;
  const u32* src = reinterpret_cast<const u32*>(cw);
  for (int idx = tid; idx < 12800; idx += 256) {
    int v = idx / 512;
    int r2 = idx - v * 512;
    u32 val = src[((size_t)(b * 25 + v) * 256 + t0) * 32 + r2];
    *reinterpret_cast<u32*>(&sld[v * 1042 + r2 * 2]) = val;
  }
  __syncthreads();
  float* obase = out + (size_t)b * 64 * 6400 + t0 * 25;
  for (int o = 0; o < 64; ++o) {
    for (int j = tid; j < 400; j += 256) {
      int t = j / 25;
      int v = j - t * 25;
      obase[(size_t)o * 6400 + j] = bf2f(sld[v * 1042 + t * 64 + o]);
    }
  }
}

extern "C" void kernel_launch(void* const* d_in, const int* in_sizes, int n_in,
                              void* d_out, int out_size, void* d_ws, size_t ws_size,
                              hipStream_t stream) {
  (void)in_sizes; (void)n_in; (void)out_size; (void)ws_size;
  const float* x    = (const float*)d_in[0];
  const float* adj  = (const float*)d_in[1];
  const float* Wg   = (const float*)d_in[2];
  const float* ag   = (const float*)d_in[3];
  const float* bn1g = (const float*)d_in[4];
  const float* bn1b = (const float*)d_in[5];
  const float* bn1m = (const float*)d_in[6];
  const float* bn1v = (const float*)d_in[7];
  const float* w3   = (const float*)d_in[8];
  const float* b3   = (const float*)d_in[9];
  const float* w5   = (const float*)d_in[10];
  const float* b5   = (const float*)d_in[11];
  const float* w7   = (const float*)d_in[12];
  const float* b7   = (const float*)d_in[13];
  const float* bn2g = (const float*)d_in[14];
  const float* bn2b = (const float*)d_in[15];
  const float* bn2m = (const float*)d_in[16];
  const float* bn2v = (const float*)d_in[17];
  const float* wf   = (const float*)d_in[18];
  const float* bfv  = (const float*)d_in[19];

  char* ws  = (char*)d_ws;
  u16* xg   = (u16*)ws;                       // 26,214,400 B
  u16* cw   = (u16*)(ws + 26214400);          // 26,214,400 B
  u16* Bpack = (u16*)(ws + 52428800);         // 122,880 B
  float* beff = (float*)(ws + 52551680);      // 64 f32
  float* s1   = beff + 64;                    // 192
  float* t1   = s1 + 192;                     // 192
  float* s2   = t1 + 192;                     // 192
  u16* Bgp   = (u16*)(ws + 52554240);         // 10,240 B
  float* out  = (float*)d_out;

  k_prep1<<<1, 256, 0, stream>>>(bn1g, bn1b, bn1m, bn1v, bn2g, bn2b, bn2m, bn2v,
                                 b3, b5, b7, wf, bfv, s1, t1, s2, beff);
  k_wpack<<<30, 256, 0, stream>>>(wf, s2, w3, w5, w7, Bpack);
  k_wg<<<3, 256, 0, stream>>>(Wg, ag, Bgp);
  k_gat2<<<1024, 256, 0, stream>>>(x, adj, Bgp, xg);
  k_conv<<<1600, 256, 0, stream>>>(xg, Bpack, beff, s1, t1, cw);
  k_tr<<<512, 256, 0, stream>>>(cw, out);
}

// Round 9
// 293.994 us; speedup vs baseline: 2.3770x; 1.3390x over previous
//
#include <hip/hip_runtime.h>

typedef unsigned int u32;
typedef unsigned short u16;
typedef short bf16x8 __attribute__((ext_vector_type(8)));
typedef float f32x4 __attribute__((ext_vector_type(4)));

#define EPSV 1e-5f
#define NEGV -9.0e15f

__device__ __forceinline__ u16 f2bf(float f) {
  u32 u = __float_as_uint(f);
  u32 r = u + 0x7FFFu + ((u >> 16) & 1u);
  return (u16)(r >> 16);
}
__device__ __forceinline__ float bf2f(u16 h) {
  return __uint_as_float(((u32)h) << 16);
}

// ---------------- prep 1: fold BN params, effective bias ----------------
__global__ void k_prep1(const float* __restrict__ bn1g, const float* __restrict__ bn1b,
                        const float* __restrict__ bn1m, const float* __restrict__ bn1v,
                        const float* __restrict__ bn2g, const float* __restrict__ bn2b,
                        const float* __restrict__ bn2m, const float* __restrict__ bn2v,
                        const float* __restrict__ b3, const float* __restrict__ b5,
                        const float* __restrict__ b7, const float* __restrict__ wf,
                        const float* __restrict__ bfv,
                        float* __restrict__ s1, float* __restrict__ t1,
                        float* __restrict__ s2, float* __restrict__ beff) {
  int tid = threadIdx.x;
  if (tid < 192) {
    float sc = bn1g[tid] / sqrtf(bn1v[tid] + EPSV);
    s1[tid] = sc;
    t1[tid] = bn1b[tid] - bn1m[tid] * sc;
    float sc2 = bn2g[tid] / sqrtf(bn2v[tid] + EPSV);
    s2[tid] = sc2;
  }
  if (tid < 64) {
    float acc = bfv[tid];
    for (int io = 0; io < 192; ++io) {
      int i = io / 64, o = io % 64;
      float sc2 = bn2g[io] / sqrtf(bn2v[io] + EPSV);
      float t2 = bn2b[io] - bn2m[io] * sc2;
      float bi = (i == 0) ? b3[o] : ((i == 1) ? b5[o] : b7[o]);
      acc += wf[tid * 192 + io] * (sc2 * bi + t2);
    }
    beff[tid] = acc;
  }
}

// ---------------- weight pack: one thread per bf16 output element ----------------
// Bpack element e = idx*8+j; idx = [kk][nf][lane]; k = kk*32+(lane>>4)*8+j,
// o2 = nf*16+(lane&15). 240 blocks cover all CUs; coalesced u16 stores.
__global__ void k_wpack(const float* __restrict__ wf, const float* __restrict__ s2,
                        const float* __restrict__ w3, const float* __restrict__ w5,
                        const float* __restrict__ w7, u16* __restrict__ Bpack) {
  int e = blockIdx.x * 256 + threadIdx.x;  // < 61440
  int idx = e >> 3, j = e & 7;
  int kk = idx >> 8;
  int rem = idx & 255;
  int nf = rem >> 6;
  int lane = rem & 63;
  int o2 = nf * 16 + (lane & 15);
  int k = kk * 32 + ((lane >> 4) << 3) + j;
  int s = k >> 6, c = k & 63;
  const float* w;
  int ks, dt, ib;
  if (s < 3)      { w = w3; ks = 3; dt = s;     ib = 0; }
  else if (s < 8) { w = w5; ks = 5; dt = s - 3; ib = 1; }
  else            { w = w7; ks = 7; dt = s - 8; ib = 2; }
  const float* wfp = wf + o2 * 192 + ib * 64;
  const float* s2p = s2 + ib * 64;
  const float* wp  = w + c * ks + dt;
  int stride = ks << 6;
  float acc = 0.f;
#pragma unroll
  for (int o = 0; o < 64; ++o)
    acc = fmaf(wfp[o] * s2p[o], wp[o * stride], acc);
  Bpack[e] = f2bf(acc);
}

// ---------------- GAT B-pack: Wg augmented with e-columns, MFMA B-frag layout ----------------
// Bg[kk][nf][lane][j], k=kk*32+(lane>>4)*8+j (in-channel c), n=nf*16+(lane&15).
// n<64: Wg[k][n]; n=64/65: (W@a1) hi/lo; n=66/67: (W@a2) hi/lo; n>=68: 0.
__global__ void k_wg(const float* __restrict__ Wg, const float* __restrict__ ag,
                     u16* __restrict__ Bgp) {
  int i = blockIdx.x * 256 + threadIdx.x;
  if (i >= 640) return;
  int lane = i & 63;
  int nf = (i >> 6) % 5;
  int kk = i / 320;
  int k0 = kk * 32 + (lane >> 4) * 8;
  int n = nf * 16 + (lane & 15);
  bf16x8 pk;
#pragma unroll
  for (int j = 0; j < 8; ++j) {
    int k = k0 + j;
    float val;
    if (n < 64) {
      val = Wg[k * 64 + n];
    } else if (n < 68) {
      int which = n - 64;
      const float* a = ag + (which >> 1) * 64;
      float wa = 0.f;
      for (int d = 0; d < 64; ++d) wa += Wg[k * 64 + d] * a[d];
      float hi = bf2f(f2bf(wa));
      val = (which & 1) ? (wa - hi) : wa;
    } else {
      val = 0.f;
    }
    pk[j] = (short)f2bf(val);
  }
  *reinterpret_cast<bf16x8*>(Bgp + (size_t)i * 8) = pk;
}

// ---------------- GAT via MFMA: 8 graphs (t's) per block ----------------
__global__ __launch_bounds__(256) void k_gat2(const float* __restrict__ x,
                                              const float* __restrict__ adj,
                                              const u16* __restrict__ Bg,
                                              u16* __restrict__ xg) {
  __shared__ __align__(16) u16 A_s[13312];    // A-tile 208x64 octet-swizzled; reused as att[8][32][40]
  __shared__ __align__(16) u16 WhT_s[16384];  // [8][64 d][32 v], v-octet swz = (voct ^ ((n>>1)&3))
  __shared__ float e1_s[208], e2_s[208];
  __shared__ u16 adj_s[640];
  int tid = threadIdx.x;
  int bid = blockIdx.x;               // 1024 = 32 b x 32 t-tiles
  int b = bid >> 5, t0 = (bid & 31) << 3;

  const float* xb = x + (size_t)b * 64 * 6400 + t0 * 25;
  for (int i = tid; i < 12800; i += 256) {
    int c = i / 200, row = i - c * 200;
    float v = xb[c * 6400 + row];
    A_s[row * 64 + ((((c >> 3) ^ (row & 7))) << 3) + (c & 7)] = f2bf(v);
  }
  for (int i = tid; i < 625; i += 256) adj_s[i] = (adj[i] > 0.f) ? 1 : 0;
  for (int i = tid; i < 3584; i += 256) {
    int v = 25 + (i % 7);
    int gn = i / 7;
    int n = gn & 63;
    WhT_s[gn * 32 + (((v >> 3) ^ ((n >> 1) & 3)) << 3) + (v & 7)] = 0;
  }
  __syncthreads();

  int wv = tid >> 6, lane = tid & 63;
  int l15 = lane & 15, l4 = lane >> 4;

  // --- GEMM1 ---
  const bf16x8* Bp = reinterpret_cast<const bf16x8*>(Bg);
  bf16x8 bg[2][5];
#pragma unroll
  for (int kk = 0; kk < 2; ++kk)
#pragma unroll
    for (int nf = 0; nf < 5; ++nf) bg[kk][nf] = Bp[(kk * 5 + nf) * 64 + lane];

  for (int mf = wv; mf < 13; mf += 4) {
    f32x4 acc[5];
#pragma unroll
    for (int nf = 0; nf < 5; ++nf)
#pragma unroll
      for (int rg = 0; rg < 4; ++rg) acc[nf][rg] = 0.f;
    int row = mf * 16 + l15;
    int r7 = row & 7;
    bf16x8 a0 = *reinterpret_cast<const bf16x8*>(&A_s[row * 64 + ((l4 ^ r7) << 3)]);
    bf16x8 a1 = *reinterpret_cast<const bf16x8*>(&A_s[row * 64 + (((4 + l4) ^ r7) << 3)]);
#pragma unroll
    for (int nf = 0; nf < 5; ++nf) {
      acc[nf] = __builtin_amdgcn_mfma_f32_16x16x32_bf16(a0, bg[0][nf], acc[nf], 0, 0, 0);
      acc[nf] = __builtin_amdgcn_mfma_f32_16x16x32_bf16(a1, bg[1][nf], acc[nf], 0, 0, 0);
    }
#pragma unroll
    for (int rg = 0; rg < 4; ++rg) {
      int row_e = mf * 16 + (l4 << 2) + rg;
      float esum = acc[4][rg] + __shfl_xor(acc[4][rg], 1);
      if (row_e < 200) {
        int g = row_e / 25;
        int vv = row_e - g * 25;
#pragma unroll
        for (int nf = 0; nf < 4; ++nf) {
          int n = nf * 16 + l15;
          WhT_s[(g * 64 + n) * 32 + (((vv >> 3) ^ ((n >> 1) & 3)) << 3) + (vv & 7)] =
              f2bf(acc[nf][rg]);
        }
        if (l15 == 0) e1_s[row_e] = esum;
        else if (l15 == 2) e2_s[row_e] = esum;
      }
    }
  }
  __syncthreads();

  // --- masked softmax: graph g = tid>>5, row u = tid&31 ---
  {
    int g = tid >> 5, u = tid & 31;
    if (u < 25) {
      float e1 = e1_s[g * 25 + u];
      float ev[25];
      float m = -1e30f;
#pragma unroll
      for (int v = 0; v < 25; ++v) {
        float e = e1 + e2_s[g * 25 + v];
        e = (e > 0.f) ? e : 0.2f * e;
        e = adj_s[u * 25 + v] ? e : NEGV;
        ev[v] = e;
        m = fmaxf(m, e);
      }
      float s = 0.f;
#pragma unroll
      for (int v = 0; v < 25; ++v) { ev[v] = __expf(ev[v] - m); s += ev[v]; }
      float inv = 1.f / s;
      u16* arow = A_s + ((size_t)(g * 32 + u)) * 40;
#pragma unroll
      for (int v = 0; v < 25; ++v) arow[v] = f2bf(ev[v] * inv);
#pragma unroll
      for (int v = 25; v < 32; ++v) arow[v] = 0;
    }
  }
  __syncthreads();

  // --- PV: per (g, mf2): D = att @ Wh ---
  for (int un = wv; un < 16; un += 4) {
    int g = un >> 1, mf2 = un & 1;
    bf16x8 afr = *reinterpret_cast<const bf16x8*>(&A_s[(g * 32 + mf2 * 16 + l15) * 40 + (l4 << 3)]);
    f32x4 pacc[4];
#pragma unroll
    for (int nf = 0; nf < 4; ++nf)
#pragma unroll
      for (int rg = 0; rg < 4; ++rg) pacc[nf][rg] = 0.f;
#pragma unroll
    for (int nf = 0; nf < 4; ++nf) {
      int n = nf * 16 + l15;
      bf16x8 bfr = *reinterpret_cast<const bf16x8*>(
          &WhT_s[(g * 64 + n) * 32 + ((l4 ^ ((n >> 1) & 3)) << 3)]);
      pacc[nf] = __builtin_amdgcn_mfma_f32_16x16x32_bf16(afr, bfr, pacc[nf], 0, 0, 0);
    }
    int t = t0 + g;
#pragma unroll
    for (int nf = 0; nf < 4; ++nf)
#pragma unroll
      for (int rg = 0; rg < 4; ++rg) {
        int u = mf2 * 16 + (l4 << 2) + rg;
        if (u < 25) {
          float val = pacc[nf][rg];
          val = (val > 0.f) ? val : __expf(val) - 1.f;
          xg[(((size_t)(b * 25 + u)) * 256 + t) * 64 + nf * 16 + l15] = f2bf(val);
        }
      }
  }
}

// ---------------- fused 3-branch conv via MFMA ----------------
__global__ __launch_bounds__(256) void k_conv(const u16* __restrict__ xg,
                                              const u16* __restrict__ Bpack,
                                              const float* __restrict__ beff,
                                              const float* __restrict__ s1g,
                                              const float* __restrict__ t1g,
                                              u16* __restrict__ cw) {
  __shared__ __align__(16) u16 Asm[134 * 192];
  __shared__ float ls1[192], lt1[192];
  int tid = threadIdx.x;
  int bid = blockIdx.x;  // 1600 = 32*25*2
  int th = bid & 1;
  int v = (bid >> 1) % 25;
  int b = (bid >> 1) / 25;
  int t0 = th << 7;
  if (tid < 192) { ls1[tid] = s1g[tid]; lt1[tid] = t1g[tid]; }
  __syncthreads();

  const u16* xbase = xg + (size_t)(b * 25 + v) * 256 * 64;
  for (int it = tid; it < 1072; it += 256) {
    int r = it >> 3, co = it & 7;
    int t_in = t0 - 3 + r;
    bf16x8 pk0, pk1, pk2;
    if (t_in >= 0 && t_in < 256) {
      bf16x8 raw = *reinterpret_cast<const bf16x8*>(xbase + (size_t)t_in * 64 + co * 8);
#pragma unroll
      for (int j = 0; j < 8; ++j) {
        float xv = bf2f((u16)raw[j]);
        int c = co * 8 + j;
        pk0[j] = (short)f2bf(fmaxf(fmaf(xv, ls1[c], lt1[c]), 0.f));
        pk1[j] = (short)f2bf(fmaxf(fmaf(xv, ls1[64 + c], lt1[64 + c]), 0.f));
        pk2[j] = (short)f2bf(fmaxf(fmaf(xv, ls1[128 + c], lt1[128 + c]), 0.f));
      }
    } else {
#pragma unroll
      for (int j = 0; j < 8; ++j) { pk0[j] = 0; pk1[j] = 0; pk2[j] = 0; }
    }
    int sw = co ^ (r & 7);
    *reinterpret_cast<bf16x8*>(&Asm[r * 192 + ((sw)      << 3)]) = pk0;
    *reinterpret_cast<bf16x8*>(&Asm[r * 192 + ((8 + sw)  << 3)]) = pk1;
    *reinterpret_cast<bf16x8*>(&Asm[r * 192 + ((16 + sw) << 3)]) = pk2;
  }
  __syncthreads();

  int w = tid >> 6, lane = tid & 63;
  int lrow = lane & 15, loct = lane >> 4;
  int mbase = w * 32 + lrow;
  f32x4 acc[2][4];
#pragma unroll
  for (int m = 0; m < 2; ++m)
#pragma unroll
    for (int n = 0; n < 4; ++n)
#pragma unroll
      for (int rg = 0; rg < 4; ++rg) acc[m][n][rg] = 0.f;

  const int SHIFT[15] = {2, 3, 4, 1, 2, 3, 4, 5, 0, 1, 2, 3, 4, 5, 6};
  const int BR[15]    = {0, 0, 0, 1, 1, 1, 1, 1, 2, 2, 2, 2, 2, 2, 2};
  const bf16x8* Bp = reinterpret_cast<const bf16x8*>(Bpack);
#pragma unroll
  for (int s = 0; s < 15; ++s) {
    int i = BR[s];
#pragma unroll
    for (int h = 0; h < 2; ++h) {
      int kk = s * 2 + h;
      bf16x8 afr[2];
#pragma unroll
      for (int mf = 0; mf < 2; ++mf) {
        int r = mbase + mf * 16 + SHIFT[s];
        int chunk = i * 8 + (((h * 4 + loct)) ^ (r & 7));
        afr[mf] = *reinterpret_cast<const bf16x8*>(&Asm[r * 192 + (chunk << 3)]);
      }
#pragma unroll
      for (int nf = 0; nf < 4; ++nf) {
        bf16x8 bfr = Bp[(kk * 4 + nf) * 64 + lane];
        acc[0][nf] = __builtin_amdgcn_mfma_f32_16x16x32_bf16(afr[0], bfr, acc[0][nf], 0, 0, 0);
        acc[1][nf] = __builtin_amdgcn_mfma_f32_16x16x32_bf16(afr[1], bfr, acc[1][nf], 0, 0, 0);
      }
    }
  }
  __syncthreads();

  float be[4];
#pragma unroll
  for (int nf = 0; nf < 4; ++nf) be[nf] = beff[nf * 16 + lrow];
#pragma unroll
  for (int mf = 0; mf < 2; ++mf)
#pragma unroll
    for (int nf = 0; nf < 4; ++nf)
#pragma unroll
      for (int rg = 0; rg < 4; ++rg) {
        int trow = w * 32 + mf * 16 + loct * 4 + rg;
        Asm[trow * 64 + nf * 16 + lrow] = f2bf(acc[mf][nf][rg] + be[nf]);
      }
  __syncthreads();
  const float4* Cs = reinterpret_cast<const float4*>(Asm);
  float4* obase = reinterpret_cast<float4*>(cw + ((size_t)(b * 25 + v) * 256 + t0) * 64);
  for (int it2 = tid; it2 < 1024; it2 += 256) obase[it2] = Cs[it2];
}

// ---------------- transpose [b][v][t][o] bf16 -> [b][o][t][v] fp32 ----------------
__global__ __launch_bounds__(256) void k_tr(const u16* __restrict__ cw,
                                            float* __restrict__ out) {
  __shared__ u16 sld[25 * 1042];
  int tid = threadIdx.x;
  int bid = blockIdx.x;
  int b = bid >> 4, tb = bid & 15;
  int t0 = tb << 4;
  const u32* src = reinterpret_cast<const u32*>(cw);
  for (int idx = tid; idx < 12800; idx += 256) {
    int v = idx / 512;
    int r2 = idx - v * 512;
    u32 val = src[((size_t)(b * 25 + v) * 256 + t0) * 32 + r2];
    *reinterpret_cast<u32*>(&sld[v * 1042 + r2 * 2]) = val;
  }
  __syncthreads();
  float* obase = out + (size_t)b * 64 * 6400 + t0 * 25;
  for (int o = 0; o < 64; ++o) {
    for (int j = tid; j < 400; j += 256) {
      int t = j / 25;
      int v = j - t * 25;
      obase[(size_t)o * 6400 + j] = bf2f(sld[v * 1042 + t * 64 + o]);
    }
  }
}

extern "C" void kernel_launch(void* const* d_in, const int* in_sizes, int n_in,
                              void* d_out, int out_size, void* d_ws, size_t ws_size,
                              hipStream_t stream) {
  (void)in_sizes; (void)n_in; (void)out_size; (void)ws_size;
  const float* x    = (const float*)d_in[0];
  const float* adj  = (const float*)d_in[1];
  const float* Wg   = (const float*)d_in[2];
  const float* ag   = (const float*)d_in[3];
  const float* bn1g = (const float*)d_in[4];
  const float* bn1b = (const float*)d_in[5];
  const float* bn1m = (const float*)d_in[6];
  const float* bn1v = (const float*)d_in[7];
  const float* w3   = (const float*)d_in[8];
  const float* b3   = (const float*)d_in[9];
  const float* w5   = (const float*)d_in[10];
  const float* b5   = (const float*)d_in[11];
  const float* w7   = (const float*)d_in[12];
  const float* b7   = (const float*)d_in[13];
  const float* bn2g = (const float*)d_in[14];
  const float* bn2b = (const float*)d_in[15];
  const float* bn2m = (const float*)d_in[16];
  const float* bn2v = (const float*)d_in[17];
  const float* wf   = (const float*)d_in[18];
  const float* bfv  = (const float*)d_in[19];

  char* ws  = (char*)d_ws;
  u16* xg   = (u16*)ws;                       // 26,214,400 B
  u16* cw   = (u16*)(ws + 26214400);          // 26,214,400 B
  u16* Bpack = (u16*)(ws + 52428800);         // 122,880 B
  float* beff = (float*)(ws + 52551680);      // 64 f32
  float* s1   = beff + 64;                    // 192
  float* t1   = s1 + 192;                     // 192
  float* s2   = t1 + 192;                     // 192
  u16* Bgp   = (u16*)(ws + 52554240);         // 10,240 B
  float* out  = (float*)d_out;

  k_prep1<<<1, 256, 0, stream>>>(bn1g, bn1b, bn1m, bn1v, bn2g, bn2b, bn2m, bn2v,
                                 b3, b5, b7, wf, bfv, s1, t1, s2, beff);
  k_wpack<<<240, 256, 0, stream>>>(wf, s2, w3, w5, w7, Bpack);
  k_wg<<<3, 256, 0, stream>>>(Wg, ag, Bgp);
  k_gat2<<<1024, 256, 0, stream>>>(x, adj, Bgp, xg);
  k_conv<<<1600, 256, 0, stream>>>(xg, Bpack, beff, s1, t1, cw);
  k_tr<<<512, 256, 0, stream>>>(cw, out);
}